// Round 6
// baseline (1326.161 us; speedup 1.0000x reference)
//
#include <hip/hip_runtime.h>
#include <math.h>

// Problem constants
#define BB 32768
#define DD 64
#define CC 64
#define HH 1024
#define LL 6
#define SPLIT 32
#define NIN 96
#define EPSV 1e-5f

typedef short short8 __attribute__((ext_vector_type(8)));
typedef float f32x4 __attribute__((ext_vector_type(4)));
typedef unsigned short u16;

// fp32 -> bf16 round-to-nearest-even (finite inputs)
__device__ __forceinline__ u16 f2bf(float f) {
    union { float f; unsigned int u; } c; c.f = f;
    unsigned int u = c.u + 0x7FFFu + ((c.u >> 16) & 1u);
    return (u16)(u >> 16);
}

// ---------------------------------------------------------------------------
// Transpose + convert: dst[c][r] (bf16, row stride Rpad) = src[r][c] (f32)
// ---------------------------------------------------------------------------
__global__ void transpose_cvt_kernel(const float* __restrict__ src, u16* __restrict__ dst,
                                     int R, int C, int Rpad,
                                     long long sstride, long long dstride)
{
    __shared__ float tile[32][33];
    const float* s = src + (size_t)blockIdx.z * sstride;
    u16* d = dst + (size_t)blockIdx.z * dstride;
    int r0 = blockIdx.x * 32, c0 = blockIdx.y * 32;
    int tc = threadIdx.x & 31, tr = threadIdx.x >> 5;   // 32 x 8
#pragma unroll
    for (int i = 0; i < 4; ++i) {
        int r = r0 + tr + i * 8;
        tile[tr + i * 8][tc] = (r < R) ? s[(size_t)r * C + c0 + tc] : 0.f;
    }
    __syncthreads();
#pragma unroll
    for (int i = 0; i < 4; ++i) {
        int cc = tr + i * 8;
        d[(size_t)(c0 + cc) * Rpad + r0 + tc] = f2bf(tile[tc][cc]);
    }
}

// ---------------------------------------------------------------------------
// One-time: fill Ain cond columns (32..95) + zero pad (96..127), all BB rows.
// ---------------------------------------------------------------------------
__global__ __launch_bounds__(256)
void init_ain_cond_kernel(const float* __restrict__ cond, u16* __restrict__ Ain)
{
    int t = blockIdx.x * 256 + threadIdx.x;   // over BB*96
    int c = t % 96, r = t / 96;
    Ain[(size_t)r * 128 + 32 + c] = (c < CC) ? f2bf(cond[(size_t)r * CC + c]) : (u16)0;
}

// One-time (layer 0): fill Ain keep columns (0..31) from x.
__global__ __launch_bounds__(256)
void build_keep_kernel(const float* __restrict__ x, u16* __restrict__ Ain, int keep_off)
{
    int t = blockIdx.x * 256 + threadIdx.x;   // over BB*32
    int c = t & 31, r = t >> 5;
    Ain[(size_t)r * 128 + c] = f2bf(x[(size_t)r * DD + 2 * c + keep_off]);
}

// ---------------------------------------------------------------------------
// Fused GEMM1+GEMM2 per 64-row block. h1 lives ENTIRELY in LDS (128 KB,
// fragment-entry layout) -> GEMM2's A-operand has zero global latency and
// the K-loop has ZERO barriers. B operands (W1t/W2t, N-major) are loaded
// direct-to-VGPR in fragment layout (L2-resident; compiler pipelines vmcnt).
// 512 threads = 8 waves; wave w owns output cols [w*128, w*128+128).
// Dynamic LDS: 128 KB h1 + 16 KB alias (Ain stage / epilogue scratch).
// ---------------------------------------------------------------------------
__global__ __launch_bounds__(512, 2)
void layer12_kernel(const u16* __restrict__ Ain,   // [BB][128] bf16
                    const u16* __restrict__ W1t,   // [1024][128] bf16 (N-major)
                    const float* __restrict__ b1l,
                    const u16* __restrict__ W2t,   // [1024][1024] bf16 (N-major)
                    const float* __restrict__ b2l,
                    u16* __restrict__ h2)          // [BB][1024] bf16 out
{
    extern __shared__ u16 lds[];
    u16* h1lds = lds;                 // 128 entries * 512 shorts = 128 KB
    u16* alias = lds + 128 * 512;     // 16 KB: Ain stage, then epilogue scratch

    const int t = threadIdx.x;
    const int w = t >> 6, lane = t & 63;
    const int lane16 = lane & 15, quad = lane >> 4;
    const int bm = blockIdx.x * 64;
    const int col0 = w * 128;

    // ---- stage Ain (16 entries, fragment order) ----
    for (int e = w; e < 16; e += 8) {
        int s = e >> 2, i = e & 3;
        const u16* g = Ain + (size_t)(bm + i * 16 + lane16) * 128 + (s * 32 + quad * 8);
        __builtin_amdgcn_global_load_lds(
            (const __attribute__((address_space(1))) unsigned int*)g,
            (__attribute__((address_space(3))) unsigned int*)(alias + e * 512), 16, 0, 0);
    }
    __syncthreads();

    f32x4 acc[4][8];
#pragma unroll
    for (int a = 0; a < 4; ++a)
#pragma unroll
        for (int b = 0; b < 8; ++b) acc[a][b] = (f32x4){0.f, 0.f, 0.f, 0.f};

    // ---- GEMM1: h1(cols col0..col0+128) = relu(Ain @ W1t^T + b1), K=128 ----
#pragma unroll
    for (int s = 0; s < 4; ++s) {
        short8 af[4];
#pragma unroll
        for (int a = 0; a < 4; ++a)
            af[a] = *(const short8*)(alias + (s * 4 + a) * 512 + lane * 8);
#pragma unroll
        for (int b = 0; b < 8; ++b) {
            short8 bf = *(const short8*)(W1t + (size_t)(col0 + b * 16 + lane16) * 128 + (s * 32 + quad * 8));
#pragma unroll
            for (int a = 0; a < 4; ++a)
                acc[a][b] = __builtin_amdgcn_mfma_f32_16x16x32_bf16(af[a], bf, acc[a][b], 0, 0, 0);
        }
    }
    {
        float bv[8];
#pragma unroll
        for (int b = 0; b < 8; ++b) bv[b] = b1l[col0 + b * 16 + lane16];
        // scatter into h1 fragment-entry layout: entry e2 = s2*4 + a,
        // s2 = col/32, lane' = (row&15) | ((col%32)/8)<<4, j = col&7
#pragma unroll
        for (int a = 0; a < 4; ++a)
#pragma unroll
            for (int b = 0; b < 8; ++b)
#pragma unroll
                for (int r = 0; r < 4; ++r) {
                    float v = fmaxf(acc[a][b][r] + bv[b], 0.f);
                    int e2 = (w * 4 + (b >> 1)) * 4 + a;
                    int lp = (quad * 4 + r) | (((b & 1) * 2 + (lane16 >> 3)) << 4);
                    h1lds[e2 * 512 + lp * 8 + (lane16 & 7)] = f2bf(v);
                }
    }
    __syncthreads();

    // ---- GEMM2: h2(cols col0..+128) = relu(h1 @ W2t^T + b2), K=1024 ----
#pragma unroll
    for (int a = 0; a < 4; ++a)
#pragma unroll
        for (int b = 0; b < 8; ++b) acc[a][b] = (f32x4){0.f, 0.f, 0.f, 0.f};

#pragma unroll 2
    for (int s = 0; s < 32; ++s) {
        short8 af[4];
#pragma unroll
        for (int a = 0; a < 4; ++a)
            af[a] = *(const short8*)(h1lds + (s * 4 + a) * 512 + lane * 8);
#pragma unroll
        for (int b = 0; b < 8; ++b) {
            short8 bf = *(const short8*)(W2t + (size_t)(col0 + b * 16 + lane16) * 1024 + (s * 32 + quad * 8));
#pragma unroll
            for (int a = 0; a < 4; ++a)
                acc[a][b] = __builtin_amdgcn_mfma_f32_16x16x32_bf16(af[a], bf, acc[a][b], 0, 0, 0);
        }
    }

    // ---- epilogue: bias+relu+f2bf -> coalesced bf16 stores (8 passes of
    //      8 rows through 2 KB per-wave scratch) ----
    {
        float bv[8];
#pragma unroll
        for (int b = 0; b < 8; ++b) bv[b] = b2l[col0 + b * 16 + lane16];
        u16* scr = alias + w * 1024;   // 8 rows x 128 cols
#pragma unroll
        for (int p = 0; p < 8; ++p) {
            int a = p >> 1, q2 = p & 1;
            __syncthreads();
            if ((quad >> 1) == q2) {
#pragma unroll
                for (int b = 0; b < 8; ++b)
#pragma unroll
                    for (int r = 0; r < 4; ++r) {
                        float v = fmaxf(acc[a][b][r] + bv[b], 0.f);
                        scr[((quad & 1) * 4 + r) * 128 + b * 16 + lane16] = f2bf(v);
                    }
            }
            __syncthreads();
            int row8 = lane >> 3, colc = (lane & 7) * 16;
            int grow = bm + a * 16 + q2 * 8 + row8;
            short8 v0 = *(const short8*)(scr + row8 * 128 + colc);
            short8 v1 = *(const short8*)(scr + row8 * 128 + colc + 8);
            *(short8*)(h2 + (size_t)grow * 1024 + col0 + colc) = v0;
            *(short8*)(h2 + (size_t)grow * 1024 + col0 + colc + 8) = v1;
        }
    }
}

// ---------------------------------------------------------------------------
// Fused GEMM3 + coupling. BM=64, 4 waves (2x2), wave tile 32x32.
// st tile in LDS (stride 66).
// ---------------------------------------------------------------------------
__global__ __launch_bounds__(256)
void gemm3_coupling(const u16* __restrict__ A,    // h2 [BB][1024]
                    const u16* __restrict__ Bt,   // wst [64][1024]
                    const float* __restrict__ bs, const float* __restrict__ bt,
                    float* __restrict__ x, float* __restrict__ log_det,
                    float* __restrict__ stat_sum, float* __restrict__ stat_sumsq,
                    int keep_off)
{
    constexpr int K = HH;
    constexpr int ST_STRIDE = 66;
    __shared__ float sst[64 * ST_STRIDE];
    __shared__ float ssum[4][64], ssum2[4][64];
    u16* lds = (u16*)sst;

    const int t = threadIdx.x;
    const int w = t >> 6, lane = t & 63;
    const int lane16 = lane & 15, quad = lane >> 4;
    const int wm = w >> 1, wn = w & 1;
    const int bm = blockIdx.x * 64;

    u16* ldsA = lds;
    u16* ldsB = lds + 8 * 512;

    f32x4 acc[2][2];
#pragma unroll
    for (int a = 0; a < 2; ++a)
#pragma unroll
        for (int b = 0; b < 2; ++b) acc[a][b] = (f32x4){0.f, 0.f, 0.f, 0.f};

    for (int k0 = 0; k0 < K; k0 += 64) {
        for (int e = w; e < 8; e += 4) {
            int s = e >> 2, i = e & 3;
            const u16* g = A + (size_t)(bm + i * 16 + lane16) * K + (k0 + s * 32 + quad * 8);
            __builtin_amdgcn_global_load_lds(
                (const __attribute__((address_space(1))) unsigned int*)g,
                (__attribute__((address_space(3))) unsigned int*)(ldsA + e * 512), 16, 0, 0);
        }
        for (int e = w; e < 8; e += 4) {
            int s = e >> 2, j = e & 3;
            const u16* g = Bt + (size_t)(j * 16 + lane16) * K + (k0 + s * 32 + quad * 8);
            __builtin_amdgcn_global_load_lds(
                (const __attribute__((address_space(1))) unsigned int*)g,
                (__attribute__((address_space(3))) unsigned int*)(ldsB + e * 512), 16, 0, 0);
        }
        __syncthreads();
#pragma unroll
        for (int s = 0; s < 2; ++s) {
            short8 af[2], bfr[2];
#pragma unroll
            for (int a = 0; a < 2; ++a)
                af[a] = *(const short8*)(ldsA + ((s * 4 + wm * 2 + a) * 64 + lane) * 8);
#pragma unroll
            for (int b = 0; b < 2; ++b)
                bfr[b] = *(const short8*)(ldsB + ((s * 4 + wn * 2 + b) * 64 + lane) * 8);
#pragma unroll
            for (int a = 0; a < 2; ++a)
#pragma unroll
                for (int b = 0; b < 2; ++b)
                    acc[a][b] = __builtin_amdgcn_mfma_f32_16x16x32_bf16(af[a], bfr[b], acc[a][b], 0, 0, 0);
        }
        __syncthreads();
    }

    // scatter acc -> LDS st tile (64 x 64)
#pragma unroll
    for (int a = 0; a < 2; ++a)
#pragma unroll
        for (int b = 0; b < 2; ++b)
#pragma unroll
            for (int r = 0; r < 4; ++r) {
                int row = wm * 32 + a * 16 + quad * 4 + r;
                int col = wn * 32 + b * 16 + lane16;
                sst[row * ST_STRIDE + col] = acc[a][b][r];
            }
    __syncthreads();

    // coupling: wave w -> rows [w*16, w*16+16), lane = feature f
    const int f = lane;
    const bool is_chg = ((f & 1) != keep_off);
    const int j = f >> 1;
    float bsj = 0.f, btj = 0.f;
    if (is_chg) { bsj = bs[j]; btj = bt[j]; }

    float lsum = 0.f, lsum2 = 0.f;
    for (int i = 0; i < 16; ++i) {
        int crow = w * 16 + i;
        int grow = bm + crow;
        float xv = x[(size_t)grow * DD + f];
        float ld = 0.f;
        if (is_chg) {
            float s_raw = sst[crow * ST_STRIDE + j];
            float t_raw = sst[crow * ST_STRIDE + SPLIT + j];
            float ls = tanhf(s_raw + bsj);
            float tv = t_raw + btj;
            xv = xv * expf(ls) + tv;
            x[(size_t)grow * DD + f] = xv;
            ld = ls;
        }
        for (int off = 32; off > 0; off >>= 1) ld += __shfl_down(ld, off, 64);
        if (f == 0) log_det[grow] += ld;
        lsum  += xv;
        lsum2 += xv * xv;
    }

    ssum[w][f]  = lsum;
    ssum2[w][f] = lsum2;
    __syncthreads();
    if (t < 64) {
        float a = ssum[0][t] + ssum[1][t] + ssum[2][t] + ssum[3][t];
        float b = ssum2[0][t] + ssum2[1][t] + ssum2[2][t] + ssum2[3][t];
        atomicAdd(stat_sum + t, a);
        atomicAdd(stat_sumsq + t, b);
    }
}

// ---------------------------------------------------------------------------
__global__ void finalize_kernel(const float* __restrict__ stat_sum, const float* __restrict__ stat_sumsq,
                                const float* __restrict__ bn_w, const float* __restrict__ bn_b,
                                float* __restrict__ scale, float* __restrict__ shift,
                                float* __restrict__ cbuf)
{
    int f = threadIdx.x;  // 64
    const float invB = 1.f / (float)BB;
    float mean = stat_sum[f] * invB;
    float var  = stat_sumsq[f] * invB - mean * mean;
    float inv  = rsqrtf(var + EPSV);
    float w    = bn_w[f];
    float sc   = inv * w;
    scale[f] = sc;
    shift[f] = bn_b[f] - mean * sc;
    float lg = logf(fabsf(w));
    for (int off = 32; off > 0; off >>= 1) lg += __shfl_down(lg, off, 64);
    if (f == 0) cbuf[0] = lg;
}

// ---------------------------------------------------------------------------
// BN normalize; optionally also writes bf16 keep-columns of next layer's Ain.
// ---------------------------------------------------------------------------
__global__ __launch_bounds__(256)
void normalize_kernel(const float* __restrict__ xin, float* __restrict__ xout,
                      const float* __restrict__ scale, const float* __restrict__ shift,
                      const float* __restrict__ cbuf, float* __restrict__ log_det,
                      u16* __restrict__ Ain, int off_next)
{
    int idx = blockIdx.x * blockDim.x + threadIdx.x;     // over B*64/4
    int f0 = (idx & 15) * 4;
    int row = idx >> 4;
    float4 v = ((const float4*)xin)[idx];
    v.x = v.x * scale[f0 + 0] + shift[f0 + 0];
    v.y = v.y * scale[f0 + 1] + shift[f0 + 1];
    v.z = v.z * scale[f0 + 2] + shift[f0 + 2];
    v.w = v.w * scale[f0 + 3] + shift[f0 + 3];
    ((float4*)xout)[idx] = v;
    if ((idx & 15) == 0) log_det[row] += cbuf[0];
    if (Ain) {
        float a0 = off_next ? v.y : v.x;
        float a1 = off_next ? v.w : v.z;
        ushort2 u; u.x = f2bf(a0); u.y = f2bf(a1);
        *(ushort2*)(Ain + (size_t)row * 128 + (f0 >> 1)) = u;
    }
}

// ---------------------------------------------------------------------------
extern "C" void kernel_launch(void* const* d_in, const int* in_sizes, int n_in,
                              void* d_out, int out_size, void* d_ws, size_t ws_size,
                              hipStream_t stream)
{
    const float* z    = (const float*)d_in[0];
    const float* cond = (const float*)d_in[1];
    const float* W1   = (const float*)d_in[2];
    const float* b1   = (const float*)d_in[3];
    const float* W2   = (const float*)d_in[4];
    const float* b2   = (const float*)d_in[5];
    const float* Ws   = (const float*)d_in[6];
    const float* bs   = (const float*)d_in[7];
    const float* Wt   = (const float*)d_in[8];
    const float* bt   = (const float*)d_in[9];
    const float* bn_w = (const float*)d_in[10];
    const float* bn_b = (const float*)d_in[11];

    float* out_x  = (float*)d_out;
    float* out_ld = out_x + (size_t)BB * DD;

    // ---- workspace layout (~95 MB) ----
    char* p = (char*)d_ws;
    size_t used = 0;
    auto alloc = [&](size_t bytes) { void* q = p + used; used += (bytes + 255) & ~(size_t)255; return q; };

    float* xbuf = (float*)alloc((size_t)BB * DD * 4);
    u16*   w1t  = (u16*)alloc((size_t)LL * HH * 128 * 2);
    u16*   w2t  = (u16*)alloc((size_t)LL * HH * HH * 2);
    u16*   wstt = (u16*)alloc((size_t)LL * 64 * HH * 2);
    float* stat_sum   = (float*)alloc(64 * 4);
    float* stat_sumsq = (float*)alloc(64 * 4);
    float* scalev     = (float*)alloc(64 * 4);
    float* shiftv     = (float*)alloc(64 * 4);
    float* cbuf       = (float*)alloc(64 * 4);
    u16*   Ain = (u16*)alloc((size_t)BB * 128 * 2);
    u16*   h2  = (u16*)alloc((size_t)BB * HH * 2);

    // mega-kernel needs 144 KB dynamic LDS
    const int MEGA_LDS = (128 * 512 + 8 * 1024) * 2;   // 147456 B
    hipFuncSetAttribute((const void*)layer12_kernel,
                        hipFuncAttributeMaxDynamicSharedMemorySize, MEGA_LDS);

    // ---- init ----
    hipMemcpyAsync(xbuf, z, (size_t)BB * DD * sizeof(float), hipMemcpyDeviceToDevice, stream);
    hipMemsetAsync(out_ld, 0, (size_t)BB * sizeof(float), stream);

    transpose_cvt_kernel<<<dim3(128/32, HH/32, LL), 256, 0, stream>>>(
        W1, w1t, NIN, HH, 128, (long long)NIN * HH, (long long)HH * 128);
    transpose_cvt_kernel<<<dim3(HH/32, HH/32, LL), 256, 0, stream>>>(
        W2, w2t, HH, HH, HH, (long long)HH * HH, (long long)HH * HH);
    transpose_cvt_kernel<<<dim3(HH/32, SPLIT/32, LL), 256, 0, stream>>>(
        Ws, wstt, HH, SPLIT, HH, (long long)HH * SPLIT, (long long)64 * HH);
    transpose_cvt_kernel<<<dim3(HH/32, SPLIT/32, LL), 256, 0, stream>>>(
        Wt, wstt + (size_t)SPLIT * HH, HH, SPLIT, HH, (long long)HH * SPLIT, (long long)64 * HH);

    init_ain_cond_kernel<<<BB * 96 / 256, 256, 0, stream>>>(cond, Ain);
    build_keep_kernel<<<BB * 32 / 256, 256, 0, stream>>>(xbuf, Ain, 0);

    for (int l = 0; l < LL; ++l) {
        const int off = l & 1;
        hipMemsetAsync(stat_sum, 0, 2 * 64 * sizeof(float), stream);

        // fused GEMM1+GEMM2 (h1 in LDS), 512 blocks x 512 threads
        layer12_kernel<<<BB / 64, 512, MEGA_LDS, stream>>>(
            Ain, w1t + (size_t)l * HH * 128, b1 + (size_t)l * HH,
            w2t + (size_t)l * HH * HH, b2 + (size_t)l * HH, h2);

        // GEMM3 + coupling fused
        gemm3_coupling<<<BB / 64, 256, 0, stream>>>(
            h2, wstt + (size_t)l * 64 * HH,
            bs + (size_t)l * SPLIT, bt + (size_t)l * SPLIT,
            xbuf, out_ld, stat_sum, stat_sumsq, off);

        finalize_kernel<<<1, 64, 0, stream>>>(
            stat_sum, stat_sumsq, bn_w + (size_t)l * DD, bn_b + (size_t)l * DD,
            scalev, shiftv, cbuf);

        float* xout = (l == LL - 1) ? out_x : xbuf;
        u16* ain_next = (l < LL - 1) ? Ain : nullptr;
        normalize_kernel<<<(BB * DD / 4) / 256, 256, 0, stream>>>(
            xbuf, xout, scalev, shiftv, cbuf, out_ld, ain_next, (l + 1) & 1);
    }
}

// Round 7
// 1286.706 us; speedup vs baseline: 1.0307x; 1.0307x over previous
//
#include <hip/hip_runtime.h>
#include <math.h>

// Problem constants
#define BB 32768
#define DD 64
#define CC 64
#define HH 1024
#define LL 6
#define SPLIT 32
#define NIN 96
#define EPSV 1e-5f

typedef short short8 __attribute__((ext_vector_type(8)));
typedef float f32x4 __attribute__((ext_vector_type(4)));
typedef unsigned short u16;

// fp32 -> bf16 round-to-nearest-even (finite inputs)
__device__ __forceinline__ u16 f2bf(float f) {
    union { float f; unsigned int u; } c; c.f = f;
    unsigned int u = c.u + 0x7FFFu + ((c.u >> 16) & 1u);
    return (u16)(u >> 16);
}

// ---------------------------------------------------------------------------
// Transpose + convert: dst[c][r] (bf16, row stride Rpad) = src[r][c] (f32)
// ---------------------------------------------------------------------------
__global__ void transpose_cvt_kernel(const float* __restrict__ src, u16* __restrict__ dst,
                                     int R, int C, int Rpad,
                                     long long sstride, long long dstride)
{
    __shared__ float tile[32][33];
    const float* s = src + (size_t)blockIdx.z * sstride;
    u16* d = dst + (size_t)blockIdx.z * dstride;
    int r0 = blockIdx.x * 32, c0 = blockIdx.y * 32;
    int tc = threadIdx.x & 31, tr = threadIdx.x >> 5;   // 32 x 8
#pragma unroll
    for (int i = 0; i < 4; ++i) {
        int r = r0 + tr + i * 8;
        tile[tr + i * 8][tc] = (r < R) ? s[(size_t)r * C + c0 + tc] : 0.f;
    }
    __syncthreads();
#pragma unroll
    for (int i = 0; i < 4; ++i) {
        int cc = tr + i * 8;
        d[(size_t)(c0 + cc) * Rpad + r0 + tc] = f2bf(tile[tc][cc]);
    }
}

// ---------------------------------------------------------------------------
// One-time: fill Ain cond columns (32..95) + zero pad (96..127), all BB rows.
// ---------------------------------------------------------------------------
__global__ __launch_bounds__(256)
void init_ain_cond_kernel(const float* __restrict__ cond, u16* __restrict__ Ain)
{
    int t = blockIdx.x * 256 + threadIdx.x;   // over BB*96
    int c = t % 96, r = t / 96;
    Ain[(size_t)r * 128 + 32 + c] = (c < CC) ? f2bf(cond[(size_t)r * CC + c]) : (u16)0;
}

// One-time (layer 0): fill Ain keep columns (0..31) from x.
__global__ __launch_bounds__(256)
void build_keep_kernel(const float* __restrict__ x, u16* __restrict__ Ain, int keep_off)
{
    int t = blockIdx.x * 256 + threadIdx.x;   // over BB*32
    int c = t & 31, r = t >> 5;
    Ain[(size_t)r * 128 + c] = f2bf(x[(size_t)r * DD + 2 * c + keep_off]);
}

// ---------------------------------------------------------------------------
// Fused GEMM1+GEMM2. h1 in LDS (128 KB, fragment-entry layout); GEMM2's
// K-loop has no barriers. Each wave owns 64 cols x 2 passes (acc = 64 regs),
// W2 fragments register-prefetched 2 K-steps ahead (ping-pong bfA/bfB),
// h1 LDS fragments prefetched 1 step ahead. 512 thr = 8 waves, 1 block/CU.
// ---------------------------------------------------------------------------
__global__ __launch_bounds__(512, 2)
void layer12_kernel(const u16* __restrict__ Ain,   // [BB][128] bf16
                    const u16* __restrict__ W1t,   // [1024][128] bf16 (N-major)
                    const float* __restrict__ b1l,
                    const u16* __restrict__ W2t,   // [1024][1024] bf16 (N-major)
                    const float* __restrict__ b2l,
                    u16* __restrict__ h2)          // [BB][1024] bf16 out
{
    extern __shared__ u16 lds[];
    u16* h1lds = lds;                 // 128 entries * 512 shorts = 128 KB
    u16* alias = lds + 128 * 512;     // 16 KB: Ain stage / epilogue scratch

    const int t = threadIdx.x;
    const int w = t >> 6, lane = t & 63;
    const int lane16 = lane & 15, quad = lane >> 4;
    const int bm = blockIdx.x * 64;

    // ---- stage Ain (16 entries, fragment order) ----
    for (int e = w; e < 16; e += 8) {
        int s = e >> 2, i = e & 3;
        const u16* g = Ain + (size_t)(bm + i * 16 + lane16) * 128 + (s * 32 + quad * 8);
        __builtin_amdgcn_global_load_lds(
            (const __attribute__((address_space(1))) unsigned int*)g,
            (__attribute__((address_space(3))) unsigned int*)(alias + e * 512), 16, 0, 0);
    }
    __syncthreads();

    // ---- GEMM1: h1 = relu(Ain @ W1t^T + b1), K=128, 2 passes of 64 cols ----
    for (int p = 0; p < 2; ++p) {
        const int cbase = p * 512 + w * 64;
        const u16* W1b = W1t + (size_t)(cbase + lane16) * 128 + quad * 8;
        f32x4 acc1[4][4];
#pragma unroll
        for (int a = 0; a < 4; ++a)
#pragma unroll
            for (int b = 0; b < 4; ++b) acc1[a][b] = (f32x4){0.f, 0.f, 0.f, 0.f};
#pragma unroll
        for (int s = 0; s < 4; ++s) {
            short8 af[4], bf[4];
#pragma unroll
            for (int a = 0; a < 4; ++a)
                af[a] = *(const short8*)(alias + (s * 4 + a) * 512 + lane * 8);
#pragma unroll
            for (int b = 0; b < 4; ++b)
                bf[b] = *(const short8*)(W1b + (size_t)b * 16 * 128 + s * 32);
#pragma unroll
            for (int b = 0; b < 4; ++b)
#pragma unroll
                for (int a = 0; a < 4; ++a)
                    acc1[a][b] = __builtin_amdgcn_mfma_f32_16x16x32_bf16(af[a], bf[b], acc1[a][b], 0, 0, 0);
        }
        float bv[4];
#pragma unroll
        for (int b = 0; b < 4; ++b) bv[b] = b1l[cbase + b * 16 + lane16];
        // scatter into h1 fragment-entry layout
#pragma unroll
        for (int a = 0; a < 4; ++a)
#pragma unroll
            for (int b = 0; b < 4; ++b)
#pragma unroll
                for (int r = 0; r < 4; ++r) {
                    float v = fmaxf(acc1[a][b][r] + bv[b], 0.f);
                    int e2 = ((cbase >> 5) + (b >> 1)) * 4 + a;
                    int lp = (quad * 4 + r) | (((b & 1) * 2 + (lane16 >> 3)) << 4);
                    h1lds[e2 * 512 + lp * 8 + (lane16 & 7)] = f2bf(v);
                }
    }
    __syncthreads();

    // ---- GEMM2: h2 = relu(h1 @ W2t^T + b2), K=1024, 2 passes of 64 cols ----
    const u16* h1p = h1lds + (size_t)lane * 8;
    for (int p = 0; p < 2; ++p) {
        const int cbase = p * 512 + w * 64;
        const u16* Wb = W2t + (size_t)(cbase + lane16) * 1024 + quad * 8;
        f32x4 acc2[4][4];
#pragma unroll
        for (int a = 0; a < 4; ++a)
#pragma unroll
            for (int b = 0; b < 4; ++b) acc2[a][b] = (f32x4){0.f, 0.f, 0.f, 0.f};

        short8 bfA[4], bfB[4], afA[4], afB[4];
#pragma unroll
        for (int b = 0; b < 4; ++b) bfA[b] = *(const short8*)(Wb + (size_t)b * 16 * 1024 + 0 * 32);
#pragma unroll
        for (int b = 0; b < 4; ++b) bfB[b] = *(const short8*)(Wb + (size_t)b * 16 * 1024 + 1 * 32);
#pragma unroll
        for (int a = 0; a < 4; ++a) afA[a] = *(const short8*)(h1p + (0 * 4 + a) * 512);

#pragma unroll
        for (int s2 = 0; s2 < 16; ++s2) {
            const int s = s2 * 2;
            // even step: consume afA/bfA
#pragma unroll
            for (int a = 0; a < 4; ++a) afB[a] = *(const short8*)(h1p + ((s + 1) * 4 + a) * 512);
#pragma unroll
            for (int b = 0; b < 4; ++b)
#pragma unroll
                for (int a = 0; a < 4; ++a)
                    acc2[a][b] = __builtin_amdgcn_mfma_f32_16x16x32_bf16(afA[a], bfA[b], acc2[a][b], 0, 0, 0);
            if (s2 < 15) {
#pragma unroll
                for (int b = 0; b < 4; ++b) bfA[b] = *(const short8*)(Wb + (size_t)b * 16 * 1024 + (s + 2) * 32);
#pragma unroll
                for (int a = 0; a < 4; ++a) afA[a] = *(const short8*)(h1p + ((s + 2) * 4 + a) * 512);
            }
            // odd step: consume afB/bfB
#pragma unroll
            for (int b = 0; b < 4; ++b)
#pragma unroll
                for (int a = 0; a < 4; ++a)
                    acc2[a][b] = __builtin_amdgcn_mfma_f32_16x16x32_bf16(afB[a], bfB[b], acc2[a][b], 0, 0, 0);
            if (s2 < 15) {
#pragma unroll
                for (int b = 0; b < 4; ++b) bfB[b] = *(const short8*)(Wb + (size_t)b * 16 * 1024 + (s + 3) * 32);
            }
        }

        // ---- epilogue pass p: bias+relu+f2bf via per-wave scratch (2 KB) ----
        float bv[4];
#pragma unroll
        for (int b = 0; b < 4; ++b) bv[b] = b2l[cbase + b * 16 + lane16];
        u16* scr = alias + w * 1024;     // 16 rows x 64 cols
#pragma unroll
        for (int a = 0; a < 4; ++a) {
#pragma unroll
            for (int b = 0; b < 4; ++b)
#pragma unroll
                for (int r = 0; r < 4; ++r) {
                    float v = fmaxf(acc2[a][b][r] + bv[b], 0.f);
                    scr[(quad * 4 + r) * 64 + b * 16 + lane16] = f2bf(v);
                }
#pragma unroll
            for (int ch = 0; ch < 2; ++ch) {
                int row = ch * 8 + (lane >> 3), colc = (lane & 7) * 8;
                short8 v = *(const short8*)(scr + row * 64 + colc);
                *(short8*)(h2 + (size_t)(bm + a * 16 + row) * 1024 + cbase + colc) = v;
            }
        }
    }
}

// ---------------------------------------------------------------------------
// Fused GEMM3 + coupling. BM=64, 4 waves (2x2), wave tile 32x32.
// st tile in LDS (stride 66).
// ---------------------------------------------------------------------------
__global__ __launch_bounds__(256)
void gemm3_coupling(const u16* __restrict__ A,    // h2 [BB][1024]
                    const u16* __restrict__ Bt,   // wst [64][1024]
                    const float* __restrict__ bs, const float* __restrict__ bt,
                    float* __restrict__ x, float* __restrict__ log_det,
                    float* __restrict__ stat_sum, float* __restrict__ stat_sumsq,
                    int keep_off)
{
    constexpr int K = HH;
    constexpr int ST_STRIDE = 66;
    __shared__ float sst[64 * ST_STRIDE];
    __shared__ float ssum[4][64], ssum2[4][64];
    u16* lds = (u16*)sst;

    const int t = threadIdx.x;
    const int w = t >> 6, lane = t & 63;
    const int lane16 = lane & 15, quad = lane >> 4;
    const int wm = w >> 1, wn = w & 1;
    const int bm = blockIdx.x * 64;

    u16* ldsA = lds;
    u16* ldsB = lds + 8 * 512;

    f32x4 acc[2][2];
#pragma unroll
    for (int a = 0; a < 2; ++a)
#pragma unroll
        for (int b = 0; b < 2; ++b) acc[a][b] = (f32x4){0.f, 0.f, 0.f, 0.f};

    for (int k0 = 0; k0 < K; k0 += 64) {
        for (int e = w; e < 8; e += 4) {
            int s = e >> 2, i = e & 3;
            const u16* g = A + (size_t)(bm + i * 16 + lane16) * K + (k0 + s * 32 + quad * 8);
            __builtin_amdgcn_global_load_lds(
                (const __attribute__((address_space(1))) unsigned int*)g,
                (__attribute__((address_space(3))) unsigned int*)(ldsA + e * 512), 16, 0, 0);
        }
        for (int e = w; e < 8; e += 4) {
            int s = e >> 2, j = e & 3;
            const u16* g = Bt + (size_t)(j * 16 + lane16) * K + (k0 + s * 32 + quad * 8);
            __builtin_amdgcn_global_load_lds(
                (const __attribute__((address_space(1))) unsigned int*)g,
                (__attribute__((address_space(3))) unsigned int*)(ldsB + e * 512), 16, 0, 0);
        }
        __syncthreads();
#pragma unroll
        for (int s = 0; s < 2; ++s) {
            short8 af[2], bfr[2];
#pragma unroll
            for (int a = 0; a < 2; ++a)
                af[a] = *(const short8*)(ldsA + ((s * 4 + wm * 2 + a) * 64 + lane) * 8);
#pragma unroll
            for (int b = 0; b < 2; ++b)
                bfr[b] = *(const short8*)(ldsB + ((s * 4 + wn * 2 + b) * 64 + lane) * 8);
#pragma unroll
            for (int a = 0; a < 2; ++a)
#pragma unroll
                for (int b = 0; b < 2; ++b)
                    acc[a][b] = __builtin_amdgcn_mfma_f32_16x16x32_bf16(af[a], bfr[b], acc[a][b], 0, 0, 0);
        }
        __syncthreads();
    }

    // scatter acc -> LDS st tile (64 x 64)
#pragma unroll
    for (int a = 0; a < 2; ++a)
#pragma unroll
        for (int b = 0; b < 2; ++b)
#pragma unroll
            for (int r = 0; r < 4; ++r) {
                int row = wm * 32 + a * 16 + quad * 4 + r;
                int col = wn * 32 + b * 16 + lane16;
                sst[row * ST_STRIDE + col] = acc[a][b][r];
            }
    __syncthreads();

    // coupling: wave w -> rows [w*16, w*16+16), lane = feature f
    const int f = lane;
    const bool is_chg = ((f & 1) != keep_off);
    const int j = f >> 1;
    float bsj = 0.f, btj = 0.f;
    if (is_chg) { bsj = bs[j]; btj = bt[j]; }

    float lsum = 0.f, lsum2 = 0.f;
    for (int i = 0; i < 16; ++i) {
        int crow = w * 16 + i;
        int grow = bm + crow;
        float xv = x[(size_t)grow * DD + f];
        float ld = 0.f;
        if (is_chg) {
            float s_raw = sst[crow * ST_STRIDE + j];
            float t_raw = sst[crow * ST_STRIDE + SPLIT + j];
            float ls = tanhf(s_raw + bsj);
            float tv = t_raw + btj;
            xv = xv * expf(ls) + tv;
            x[(size_t)grow * DD + f] = xv;
            ld = ls;
        }
        for (int off = 32; off > 0; off >>= 1) ld += __shfl_down(ld, off, 64);
        if (f == 0) log_det[grow] += ld;
        lsum  += xv;
        lsum2 += xv * xv;
    }

    ssum[w][f]  = lsum;
    ssum2[w][f] = lsum2;
    __syncthreads();
    if (t < 64) {
        float a = ssum[0][t] + ssum[1][t] + ssum[2][t] + ssum[3][t];
        float b = ssum2[0][t] + ssum2[1][t] + ssum2[2][t] + ssum2[3][t];
        atomicAdd(stat_sum + t, a);
        atomicAdd(stat_sumsq + t, b);
    }
}

// ---------------------------------------------------------------------------
__global__ void finalize_kernel(const float* __restrict__ stat_sum, const float* __restrict__ stat_sumsq,
                                const float* __restrict__ bn_w, const float* __restrict__ bn_b,
                                float* __restrict__ scale, float* __restrict__ shift,
                                float* __restrict__ cbuf)
{
    int f = threadIdx.x;  // 64
    const float invB = 1.f / (float)BB;
    float mean = stat_sum[f] * invB;
    float var  = stat_sumsq[f] * invB - mean * mean;
    float inv  = rsqrtf(var + EPSV);
    float w    = bn_w[f];
    float sc   = inv * w;
    scale[f] = sc;
    shift[f] = bn_b[f] - mean * sc;
    float lg = logf(fabsf(w));
    for (int off = 32; off > 0; off >>= 1) lg += __shfl_down(lg, off, 64);
    if (f == 0) cbuf[0] = lg;
}

// ---------------------------------------------------------------------------
// BN normalize; optionally also writes bf16 keep-columns of next layer's Ain.
// ---------------------------------------------------------------------------
__global__ __launch_bounds__(256)
void normalize_kernel(const float* __restrict__ xin, float* __restrict__ xout,
                      const float* __restrict__ scale, const float* __restrict__ shift,
                      const float* __restrict__ cbuf, float* __restrict__ log_det,
                      u16* __restrict__ Ain, int off_next)
{
    int idx = blockIdx.x * blockDim.x + threadIdx.x;     // over B*64/4
    int f0 = (idx & 15) * 4;
    int row = idx >> 4;
    float4 v = ((const float4*)xin)[idx];
    v.x = v.x * scale[f0 + 0] + shift[f0 + 0];
    v.y = v.y * scale[f0 + 1] + shift[f0 + 1];
    v.z = v.z * scale[f0 + 2] + shift[f0 + 2];
    v.w = v.w * scale[f0 + 3] + shift[f0 + 3];
    ((float4*)xout)[idx] = v;
    if ((idx & 15) == 0) log_det[row] += cbuf[0];
    if (Ain) {
        float a0 = off_next ? v.y : v.x;
        float a1 = off_next ? v.w : v.z;
        ushort2 u; u.x = f2bf(a0); u.y = f2bf(a1);
        *(ushort2*)(Ain + (size_t)row * 128 + (f0 >> 1)) = u;
    }
}

// ---------------------------------------------------------------------------
extern "C" void kernel_launch(void* const* d_in, const int* in_sizes, int n_in,
                              void* d_out, int out_size, void* d_ws, size_t ws_size,
                              hipStream_t stream)
{
    const float* z    = (const float*)d_in[0];
    const float* cond = (const float*)d_in[1];
    const float* W1   = (const float*)d_in[2];
    const float* b1   = (const float*)d_in[3];
    const float* W2   = (const float*)d_in[4];
    const float* b2   = (const float*)d_in[5];
    const float* Ws   = (const float*)d_in[6];
    const float* bs   = (const float*)d_in[7];
    const float* Wt   = (const float*)d_in[8];
    const float* bt   = (const float*)d_in[9];
    const float* bn_w = (const float*)d_in[10];
    const float* bn_b = (const float*)d_in[11];

    float* out_x  = (float*)d_out;
    float* out_ld = out_x + (size_t)BB * DD;

    // ---- workspace layout (~95 MB) ----
    char* p = (char*)d_ws;
    size_t used = 0;
    auto alloc = [&](size_t bytes) { void* q = p + used; used += (bytes + 255) & ~(size_t)255; return q; };

    float* xbuf = (float*)alloc((size_t)BB * DD * 4);
    u16*   w1t  = (u16*)alloc((size_t)LL * HH * 128 * 2);
    u16*   w2t  = (u16*)alloc((size_t)LL * HH * HH * 2);
    u16*   wstt = (u16*)alloc((size_t)LL * 64 * HH * 2);
    float* stat_sum   = (float*)alloc(64 * 4);
    float* stat_sumsq = (float*)alloc(64 * 4);
    float* scalev     = (float*)alloc(64 * 4);
    float* shiftv     = (float*)alloc(64 * 4);
    float* cbuf       = (float*)alloc(64 * 4);
    u16*   Ain = (u16*)alloc((size_t)BB * 128 * 2);
    u16*   h2  = (u16*)alloc((size_t)BB * HH * 2);

    const int MEGA_LDS = (128 * 512 + 8 * 1024) * 2;   // 147456 B
    hipFuncSetAttribute((const void*)layer12_kernel,
                        hipFuncAttributeMaxDynamicSharedMemorySize, MEGA_LDS);

    // ---- init ----
    hipMemcpyAsync(xbuf, z, (size_t)BB * DD * sizeof(float), hipMemcpyDeviceToDevice, stream);
    hipMemsetAsync(out_ld, 0, (size_t)BB * sizeof(float), stream);

    transpose_cvt_kernel<<<dim3(128/32, HH/32, LL), 256, 0, stream>>>(
        W1, w1t, NIN, HH, 128, (long long)NIN * HH, (long long)HH * 128);
    transpose_cvt_kernel<<<dim3(HH/32, HH/32, LL), 256, 0, stream>>>(
        W2, w2t, HH, HH, HH, (long long)HH * HH, (long long)HH * HH);
    transpose_cvt_kernel<<<dim3(HH/32, SPLIT/32, LL), 256, 0, stream>>>(
        Ws, wstt, HH, SPLIT, HH, (long long)HH * SPLIT, (long long)64 * HH);
    transpose_cvt_kernel<<<dim3(HH/32, SPLIT/32, LL), 256, 0, stream>>>(
        Wt, wstt + (size_t)SPLIT * HH, HH, SPLIT, HH, (long long)HH * SPLIT, (long long)64 * HH);

    init_ain_cond_kernel<<<BB * 96 / 256, 256, 0, stream>>>(cond, Ain);
    build_keep_kernel<<<BB * 32 / 256, 256, 0, stream>>>(xbuf, Ain, 0);

    for (int l = 0; l < LL; ++l) {
        const int off = l & 1;
        hipMemsetAsync(stat_sum, 0, 2 * 64 * sizeof(float), stream);

        layer12_kernel<<<BB / 64, 512, MEGA_LDS, stream>>>(
            Ain, w1t + (size_t)l * HH * 128, b1 + (size_t)l * HH,
            w2t + (size_t)l * HH * HH, b2 + (size_t)l * HH, h2);

        gemm3_coupling<<<BB / 64, 256, 0, stream>>>(
            h2, wstt + (size_t)l * 64 * HH,
            bs + (size_t)l * SPLIT, bt + (size_t)l * SPLIT,
            xbuf, out_ld, stat_sum, stat_sumsq, off);

        finalize_kernel<<<1, 64, 0, stream>>>(
            stat_sum, stat_sumsq, bn_w + (size_t)l * DD, bn_b + (size_t)l * DD,
            scalev, shiftv, cbuf);

        float* xout = (l == LL - 1) ? out_x : xbuf;
        u16* ain_next = (l < LL - 1) ? Ain : nullptr;
        normalize_kernel<<<(BB * DD / 4) / 256, 256, 0, stream>>>(
            xbuf, xout, scalev, shiftv, cbuf, out_ld, ain_next, (l + 1) & 1);
    }
}

// Round 8
// 1127.727 us; speedup vs baseline: 1.1760x; 1.1410x over previous
//
#include <hip/hip_runtime.h>
#include <math.h>

// Problem constants
#define BB 32768
#define DD 64
#define CC 64
#define HH 1024
#define LL 6
#define SPLIT 32
#define NIN 96
#define EPSV 1e-5f

typedef short short8 __attribute__((ext_vector_type(8)));
typedef float f32x4 __attribute__((ext_vector_type(4)));
typedef unsigned short u16;

// fp32 -> bf16 round-to-nearest-even (finite inputs)
__device__ __forceinline__ u16 f2bf(float f) {
    union { float f; unsigned int u; } c; c.f = f;
    unsigned int u = c.u + 0x7FFFu + ((c.u >> 16) & 1u);
    return (u16)(u >> 16);
}

__device__ __forceinline__ void gl_lds16(const u16* g, u16* l) {
    __builtin_amdgcn_global_load_lds(
        (const __attribute__((address_space(1))) unsigned int*)g,
        (__attribute__((address_space(3))) unsigned int*)l, 16, 0, 0);
}

// ---------------------------------------------------------------------------
// Transpose + convert: dst[c][r] (bf16, row stride Rpad) = src[r][c] (f32)
// ---------------------------------------------------------------------------
__global__ void transpose_cvt_kernel(const float* __restrict__ src, u16* __restrict__ dst,
                                     int R, int C, int Rpad,
                                     long long sstride, long long dstride)
{
    __shared__ float tile[32][33];
    const float* s = src + (size_t)blockIdx.z * sstride;
    u16* d = dst + (size_t)blockIdx.z * dstride;
    int r0 = blockIdx.x * 32, c0 = blockIdx.y * 32;
    int tc = threadIdx.x & 31, tr = threadIdx.x >> 5;   // 32 x 8
#pragma unroll
    for (int i = 0; i < 4; ++i) {
        int r = r0 + tr + i * 8;
        tile[tr + i * 8][tc] = (r < R) ? s[(size_t)r * C + c0 + tc] : 0.f;
    }
    __syncthreads();
#pragma unroll
    for (int i = 0; i < 4; ++i) {
        int cc = tr + i * 8;
        d[(size_t)(c0 + cc) * Rpad + r0 + tc] = f2bf(tile[tc][cc]);
    }
}

// ---------------------------------------------------------------------------
// One-time: fill Ain cond columns (32..95) + zero pad (96..127), all BB rows.
// ---------------------------------------------------------------------------
__global__ __launch_bounds__(256)
void init_ain_cond_kernel(const float* __restrict__ cond, u16* __restrict__ Ain)
{
    int t = blockIdx.x * 256 + threadIdx.x;   // over BB*96
    int c = t % 96, r = t / 96;
    Ain[(size_t)r * 128 + 32 + c] = (c < CC) ? f2bf(cond[(size_t)r * CC + c]) : (u16)0;
}

// One-time (layer 0): fill Ain keep columns (0..31) from x.
__global__ __launch_bounds__(256)
void build_keep_kernel(const float* __restrict__ x, u16* __restrict__ Ain, int keep_off)
{
    int t = blockIdx.x * 256 + threadIdx.x;   // over BB*32
    int c = t & 31, r = t >> 5;
    Ain[(size_t)r * 128 + c] = f2bf(x[(size_t)r * DD + 2 * c + keep_off]);
}

// ---------------------------------------------------------------------------
// Tiled bf16 MFMA GEMM: C = relu(A @ Bt^T + bias), N = 1024 fixed.
// Block tile 128 rows x 256 cols; 8 waves (2x4), wave tile 64x64 (acc=64).
// BK=32, double-buffered LDS (A 8KB x2, B 16KB x2 = 48 KB), ONE barrier per
// K-iter: stage(it+1) issues right after the barrier and has the whole
// compute(it) (~1.5k cyc LDS+MFMA) to complete before the next barrier's
// vmcnt drain. 2 blocks/CU co-resident add cross-block overlap.
// ---------------------------------------------------------------------------
__global__ __launch_bounds__(512, 4)
void gemm_tiled(const u16* __restrict__ A,    // [M][K] bf16 row-major (chunk-local)
                const u16* __restrict__ Bt,   // [1024][K] bf16 N-major
                const float* __restrict__ bias,
                u16* __restrict__ Cc,         // [M][1024] bf16 out
                int K)
{
    __shared__ u16 sA[2][8 * 512];     // 16 KB
    __shared__ u16 sB[2][16 * 512];    // 32 KB

    const int t = threadIdx.x;
    const int w = t >> 6, lane = t & 63;
    const int lane16 = lane & 15, quad = lane >> 4;
    const int wm = w >> 2, wn = w & 3;          // 2 x 4 waves

    // XCD swizzle: grid = nby x 4, col index fastest within an XCD
    int id = blockIdx.x;
    int nby = gridDim.x >> 2;
    int xcd = id & 7, slot = id >> 3;
    int bx = slot & 3, byq = slot >> 2;
    int by = xcd * (nby >> 3) + byq;
    const int bm = by * 128, bn = bx * 256;

    const int niter = K >> 5;

    // stage K-chunk it into buffer buf (24 entries: 8 A row-tiles + 16 B col-tiles)
    auto stage = [&](int it, int buf) {
        int k0 = it * 32;
#pragma unroll
        for (int e3 = 0; e3 < 3; ++e3) {
            int e = w + e3 * 8;
            if (e < 8) {
                const u16* g = A + (size_t)(bm + e * 16 + lane16) * K + k0 + quad * 8;
                gl_lds16(g, &sA[buf][e * 512]);
            } else {
                int j = e - 8;
                const u16* g = Bt + (size_t)(bn + j * 16 + lane16) * K + k0 + quad * 8;
                gl_lds16(g, &sB[buf][j * 512]);
            }
        }
    };

    f32x4 acc[4][4];
#pragma unroll
    for (int a = 0; a < 4; ++a)
#pragma unroll
        for (int b = 0; b < 4; ++b) acc[a][b] = (f32x4){0.f, 0.f, 0.f, 0.f};

    stage(0, 0);
    for (int it = 0; it < niter; ++it) {
        const int buf = it & 1;
        __syncthreads();                       // drains stage(it); syncs compute(it-1)
        if (it + 1 < niter) stage(it + 1, buf ^ 1);
        short8 af[4], bf[4];
#pragma unroll
        for (int a = 0; a < 4; ++a)
            af[a] = *(const short8*)(&sA[buf][(wm * 4 + a) * 512 + lane * 8]);
#pragma unroll
        for (int b = 0; b < 4; ++b)
            bf[b] = *(const short8*)(&sB[buf][(wn * 4 + b) * 512 + lane * 8]);
#pragma unroll
        for (int a = 0; a < 4; ++a)
#pragma unroll
            for (int b = 0; b < 4; ++b)
                acc[a][b] = __builtin_amdgcn_mfma_f32_16x16x32_bf16(af[a], bf[b], acc[a][b], 0, 0, 0);
    }
    __syncthreads();                           // all compute done; LDS reusable

    // ---- epilogue: bias+relu+f2bf via per-wave scratch, coalesced stores ----
    constexpr int ES = 72;                     // shorts; rows 144 B apart
    float bv[4];
#pragma unroll
    for (int b = 0; b < 4; ++b) bv[b] = bias[bn + wn * 64 + b * 16 + lane16];
    u16* scr = ((u16*)sB) + w * (16 * ES);     // 2304 B per wave (16B-aligned)
#pragma unroll
    for (int a = 0; a < 4; ++a) {
#pragma unroll
        for (int b = 0; b < 4; ++b)
#pragma unroll
            for (int r = 0; r < 4; ++r) {
                float v = fmaxf(acc[a][b][r] + bv[b], 0.f);
                scr[(quad * 4 + r) * ES + b * 16 + lane16] = f2bf(v);
            }
#pragma unroll
        for (int ch = 0; ch < 2; ++ch) {
            int row = ch * 8 + (lane >> 3), colc = (lane & 7) * 8;
            short8 v = *(const short8*)(scr + row * ES + colc);
            *(short8*)(Cc + (size_t)(bm + wm * 64 + a * 16 + row) * 1024 + bn + wn * 64 + colc) = v;
        }
    }
}

// ---------------------------------------------------------------------------
// Fused GEMM3 + coupling. BM=64, 4 waves (2x2), wave tile 32x32.
// ---------------------------------------------------------------------------
__global__ __launch_bounds__(256)
void gemm3_coupling(const u16* __restrict__ A,    // h2 chunk [CH][1024]
                    const u16* __restrict__ Bt,   // wst [64][1024]
                    const float* __restrict__ bs, const float* __restrict__ bt,
                    float* __restrict__ x, float* __restrict__ log_det,
                    float* __restrict__ stat_sum, float* __restrict__ stat_sumsq,
                    int keep_off, int row0)
{
    constexpr int K = HH;
    constexpr int ST_STRIDE = 66;
    __shared__ float sst[64 * ST_STRIDE];
    __shared__ float ssum[4][64], ssum2[4][64];
    u16* lds = (u16*)sst;

    const int t = threadIdx.x;
    const int w = t >> 6, lane = t & 63;
    const int lane16 = lane & 15, quad = lane >> 4;
    const int wm = w >> 1, wn = w & 1;
    const int bm = blockIdx.x * 64;

    u16* ldsA = lds;
    u16* ldsB = lds + 8 * 512;

    f32x4 acc[2][2];
#pragma unroll
    for (int a = 0; a < 2; ++a)
#pragma unroll
        for (int b = 0; b < 2; ++b) acc[a][b] = (f32x4){0.f, 0.f, 0.f, 0.f};

    for (int k0 = 0; k0 < K; k0 += 64) {
        for (int e = w; e < 8; e += 4) {
            int s = e >> 2, i = e & 3;
            const u16* g = A + (size_t)(bm + i * 16 + lane16) * K + (k0 + s * 32 + quad * 8);
            gl_lds16(g, ldsA + e * 512);
        }
        for (int e = w; e < 8; e += 4) {
            int s = e >> 2, j = e & 3;
            const u16* g = Bt + (size_t)(j * 16 + lane16) * K + (k0 + s * 32 + quad * 8);
            gl_lds16(g, ldsB + e * 512);
        }
        __syncthreads();
#pragma unroll
        for (int s = 0; s < 2; ++s) {
            short8 af[2], bfr[2];
#pragma unroll
            for (int a = 0; a < 2; ++a)
                af[a] = *(const short8*)(ldsA + ((s * 4 + wm * 2 + a) * 64 + lane) * 8);
#pragma unroll
            for (int b = 0; b < 2; ++b)
                bfr[b] = *(const short8*)(ldsB + ((s * 4 + wn * 2 + b) * 64 + lane) * 8);
#pragma unroll
            for (int a = 0; a < 2; ++a)
#pragma unroll
                for (int b = 0; b < 2; ++b)
                    acc[a][b] = __builtin_amdgcn_mfma_f32_16x16x32_bf16(af[a], bfr[b], acc[a][b], 0, 0, 0);
        }
        __syncthreads();
    }

    // scatter acc -> LDS st tile (64 x 64)
#pragma unroll
    for (int a = 0; a < 2; ++a)
#pragma unroll
        for (int b = 0; b < 2; ++b)
#pragma unroll
            for (int r = 0; r < 4; ++r) {
                int row = wm * 32 + a * 16 + quad * 4 + r;
                int col = wn * 32 + b * 16 + lane16;
                sst[row * ST_STRIDE + col] = acc[a][b][r];
            }
    __syncthreads();

    const int f = lane;
    const bool is_chg = ((f & 1) != keep_off);
    const int j = f >> 1;
    float bsj = 0.f, btj = 0.f;
    if (is_chg) { bsj = bs[j]; btj = bt[j]; }

    float lsum = 0.f, lsum2 = 0.f;
    for (int i = 0; i < 16; ++i) {
        int crow = w * 16 + i;
        int grow = row0 + bm + crow;
        float xv = x[(size_t)grow * DD + f];
        float ld = 0.f;
        if (is_chg) {
            float s_raw = sst[crow * ST_STRIDE + j];
            float t_raw = sst[crow * ST_STRIDE + SPLIT + j];
            float ls = tanhf(s_raw + bsj);
            float tv = t_raw + btj;
            xv = xv * expf(ls) + tv;
            x[(size_t)grow * DD + f] = xv;
            ld = ls;
        }
        for (int off = 32; off > 0; off >>= 1) ld += __shfl_down(ld, off, 64);
        if (f == 0) log_det[grow] += ld;
        lsum  += xv;
        lsum2 += xv * xv;
    }

    ssum[w][f]  = lsum;
    ssum2[w][f] = lsum2;
    __syncthreads();
    if (t < 64) {
        float a = ssum[0][t] + ssum[1][t] + ssum[2][t] + ssum[3][t];
        float b = ssum2[0][t] + ssum2[1][t] + ssum2[2][t] + ssum2[3][t];
        atomicAdd(stat_sum + t, a);
        atomicAdd(stat_sumsq + t, b);
    }
}

// ---------------------------------------------------------------------------
__global__ void finalize_kernel(const float* __restrict__ stat_sum, const float* __restrict__ stat_sumsq,
                                const float* __restrict__ bn_w, const float* __restrict__ bn_b,
                                float* __restrict__ scale, float* __restrict__ shift,
                                float* __restrict__ cbuf)
{
    int f = threadIdx.x;  // 64
    const float invB = 1.f / (float)BB;
    float mean = stat_sum[f] * invB;
    float var  = stat_sumsq[f] * invB - mean * mean;
    float inv  = rsqrtf(var + EPSV);
    float w    = bn_w[f];
    float sc   = inv * w;
    scale[f] = sc;
    shift[f] = bn_b[f] - mean * sc;
    float lg = logf(fabsf(w));
    for (int off = 32; off > 0; off >>= 1) lg += __shfl_down(lg, off, 64);
    if (f == 0) cbuf[0] = lg;
}

// ---------------------------------------------------------------------------
// BN normalize; optionally also writes bf16 keep-columns of next layer's Ain.
// ---------------------------------------------------------------------------
__global__ __launch_bounds__(256)
void normalize_kernel(const float* __restrict__ xin, float* __restrict__ xout,
                      const float* __restrict__ scale, const float* __restrict__ shift,
                      const float* __restrict__ cbuf, float* __restrict__ log_det,
                      u16* __restrict__ Ain, int off_next)
{
    int idx = blockIdx.x * blockDim.x + threadIdx.x;     // over B*64/4
    int f0 = (idx & 15) * 4;
    int row = idx >> 4;
    float4 v = ((const float4*)xin)[idx];
    v.x = v.x * scale[f0 + 0] + shift[f0 + 0];
    v.y = v.y * scale[f0 + 1] + shift[f0 + 1];
    v.z = v.z * scale[f0 + 2] + shift[f0 + 2];
    v.w = v.w * scale[f0 + 3] + shift[f0 + 3];
    ((float4*)xout)[idx] = v;
    if ((idx & 15) == 0) log_det[row] += cbuf[0];
    if (Ain) {
        float a0 = off_next ? v.y : v.x;
        float a1 = off_next ? v.w : v.z;
        ushort2 u; u.x = f2bf(a0); u.y = f2bf(a1);
        *(ushort2*)(Ain + (size_t)row * 128 + (f0 >> 1)) = u;
    }
}

// ---------------------------------------------------------------------------
extern "C" void kernel_launch(void* const* d_in, const int* in_sizes, int n_in,
                              void* d_out, int out_size, void* d_ws, size_t ws_size,
                              hipStream_t stream)
{
    const float* z    = (const float*)d_in[0];
    const float* cond = (const float*)d_in[1];
    const float* W1   = (const float*)d_in[2];
    const float* b1   = (const float*)d_in[3];
    const float* W2   = (const float*)d_in[4];
    const float* b2   = (const float*)d_in[5];
    const float* Ws   = (const float*)d_in[6];
    const float* bs   = (const float*)d_in[7];
    const float* Wt   = (const float*)d_in[8];
    const float* bt   = (const float*)d_in[9];
    const float* bn_w = (const float*)d_in[10];
    const float* bn_b = (const float*)d_in[11];

    float* out_x  = (float*)d_out;
    float* out_ld = out_x + (size_t)BB * DD;

    // ---- workspace: fixed part ~30.5 MB + h1/h2 (CH*4 KB) ----
    char* p = (char*)d_ws;
    size_t used = 0;
    auto alloc = [&](size_t bytes) { void* q = p + used; used += (bytes + 255) & ~(size_t)255; return q; };

    float* xbuf = (float*)alloc((size_t)BB * DD * 4);
    u16*   w1t  = (u16*)alloc((size_t)LL * HH * 128 * 2);
    u16*   w2t  = (u16*)alloc((size_t)LL * HH * HH * 2);
    u16*   wstt = (u16*)alloc((size_t)LL * 64 * HH * 2);
    u16*   Ain  = (u16*)alloc((size_t)BB * 128 * 2);
    float* stat_sum   = (float*)alloc(64 * 4);
    float* stat_sumsq = (float*)alloc(64 * 4);
    float* scalev     = (float*)alloc(64 * 4);
    float* shiftv     = (float*)alloc(64 * 4);
    float* cbuf       = (float*)alloc(64 * 4);

    int CH = BB;
    while (CH > 8192 && used + (size_t)CH * 4096 + 4096 > ws_size) CH >>= 1;
    u16* h1 = (u16*)alloc((size_t)CH * HH * 2);
    u16* h2 = (u16*)alloc((size_t)CH * HH * 2);

    // ---- init ----
    hipMemcpyAsync(xbuf, z, (size_t)BB * DD * sizeof(float), hipMemcpyDeviceToDevice, stream);
    hipMemsetAsync(out_ld, 0, (size_t)BB * sizeof(float), stream);

    transpose_cvt_kernel<<<dim3(128/32, HH/32, LL), 256, 0, stream>>>(
        W1, w1t, NIN, HH, 128, (long long)NIN * HH, (long long)HH * 128);
    transpose_cvt_kernel<<<dim3(HH/32, HH/32, LL), 256, 0, stream>>>(
        W2, w2t, HH, HH, HH, (long long)HH * HH, (long long)HH * HH);
    transpose_cvt_kernel<<<dim3(HH/32, SPLIT/32, LL), 256, 0, stream>>>(
        Ws, wstt, HH, SPLIT, HH, (long long)HH * SPLIT, (long long)64 * HH);
    transpose_cvt_kernel<<<dim3(HH/32, SPLIT/32, LL), 256, 0, stream>>>(
        Wt, wstt + (size_t)SPLIT * HH, HH, SPLIT, HH, (long long)HH * SPLIT, (long long)64 * HH);

    init_ain_cond_kernel<<<BB * 96 / 256, 256, 0, stream>>>(cond, Ain);
    build_keep_kernel<<<BB * 32 / 256, 256, 0, stream>>>(xbuf, Ain, 0);

    for (int l = 0; l < LL; ++l) {
        const int off = l & 1;
        hipMemsetAsync(stat_sum, 0, 2 * 64 * sizeof(float), stream);

        for (int c = 0; c < BB / CH; ++c) {
            const int row0 = c * CH;

            // GEMM1: h1 = relu(Ain @ W1t^T + b1)   M=CH, K=128
            gemm_tiled<<<(CH / 128) * 4, 512, 0, stream>>>(
                Ain + (size_t)row0 * 128, w1t + (size_t)l * HH * 128,
                b1 + (size_t)l * HH, h1, 128);

            // GEMM2: h2 = relu(h1 @ W2t^T + b2)    M=CH, K=1024
            gemm_tiled<<<(CH / 128) * 4, 512, 0, stream>>>(
                h1, w2t + (size_t)l * HH * HH,
                b2 + (size_t)l * HH, h2, HH);

            // GEMM3 + coupling fused
            gemm3_coupling<<<CH / 64, 256, 0, stream>>>(
                h2, wstt + (size_t)l * 64 * HH,
                bs + (size_t)l * SPLIT, bt + (size_t)l * SPLIT,
                xbuf, out_ld, stat_sum, stat_sumsq, off, row0);
        }

        finalize_kernel<<<1, 64, 0, stream>>>(
            stat_sum, stat_sumsq, bn_w + (size_t)l * DD, bn_b + (size_t)l * DD,
            scalev, shiftv, cbuf);

        float* xout = (l == LL - 1) ? out_x : xbuf;
        u16* ain_next = (l < LL - 1) ? Ain : nullptr;
        normalize_kernel<<<(BB * DD / 4) / 256, 256, 0, stream>>>(
            xbuf, xout, scalev, shiftv, cbuf, out_ld, ain_next, (l + 1) & 1);
    }
}